// Round 2
// baseline (311.463 us; speedup 1.0000x reference)
//
#include <hip/hip_runtime.h>
#include <cstdint>
#include <cstddef>

#define Bb 2
#define Ss 2048
#define Dd 1024
#define Hh 16

typedef __attribute__((ext_vector_type(8))) short short8;
typedef __attribute__((ext_vector_type(4))) short short4v;
typedef __attribute__((ext_vector_type(4))) float float4v;

__device__ inline short f2bf(float f) {
  unsigned u = __builtin_bit_cast(unsigned, f);
  u = (u + 0x7fffu + ((u >> 16) & 1u)) >> 16;
  return (short)u;
}

__device__ inline float bf2f(short s) {
  unsigned u = ((unsigned)(unsigned short)s) << 16;
  return __builtin_bit_cast(float, u);
}

__device__ inline void gl_lds16(const void* g, void* l) {
  __builtin_amdgcn_global_load_lds(
      (__attribute__((address_space(1))) void*)(void*)(g),
      (__attribute__((address_space(3))) void*)(l), 16, 0, 0);
}

#define MFMA(a, b, c) __builtin_amdgcn_mfma_f32_16x16x32_bf16((a), (b), (c), 0, 0, 0)

// ---------------- LN row body (f32 in -> bf16 out) ----------------
__device__ __forceinline__ void ln_row(const float* __restrict__ x,
                                       const float* __restrict__ g,
                                       const float* __restrict__ be,
                                       short* __restrict__ out, int row,
                                       float* red) {
  int tid = threadIdx.x;
  const float4* xr = (const float4*)(x + (size_t)row * Dd);
  float4 v = xr[tid];
  float s = v.x + v.y + v.z + v.w;
  float q = v.x * v.x + v.y * v.y + v.z * v.z + v.w * v.w;
#pragma unroll
  for (int off = 1; off < 64; off <<= 1) {
    s += __shfl_xor(s, off);
    q += __shfl_xor(q, off);
  }
  int w = tid >> 6;
  if ((tid & 63) == 0) { red[w] = s; red[4 + w] = q; }
  __syncthreads();
  s = red[0] + red[1] + red[2] + red[3];
  q = red[4] + red[5] + red[6] + red[7];
  float mu = s * (1.0f / Dd);
  float var = q * (1.0f / Dd) - mu * mu;
  float rstd = rsqrtf(var + 1e-5f);
  float4 gv = ((const float4*)g)[tid], bv = ((const float4*)be)[tid];
  short4v o;
  o.x = f2bf((v.x - mu) * rstd * gv.x + bv.x);
  o.y = f2bf((v.y - mu) * rstd * gv.y + bv.y);
  o.z = f2bf((v.z - mu) * rstd * gv.z + bv.z);
  o.w = f2bf((v.w - mu) * rstd * gv.w + bv.w);
  *(short4v*)(out + (size_t)row * Dd + tid * 4) = o;
}

// ---------------- prep: 4 weight transposes + LN1, by block range ------------
__global__ __launch_bounds__(256) void prep_kernel(
    const float* __restrict__ W0, short* __restrict__ T0,
    const float* __restrict__ W1, short* __restrict__ T1,
    const float* __restrict__ W2, short* __restrict__ T2,
    const float* __restrict__ W3, short* __restrict__ T3,
    const float* __restrict__ x, const float* __restrict__ g1,
    const float* __restrict__ be1, short* __restrict__ h1) {
  __shared__ __align__(16) float t[32][33];
  int id = blockIdx.x;
  if (id >= 12288) {
    ln_row(x, g1, be1, h1, id - 12288, &t[0][0]);
    return;
  }
  const float* W; short* Wt; int N, K, tix;
  if (id < 3072)      { W = W0; Wt = T0; N = 3072; K = 1024; tix = id; }
  else if (id < 4096) { W = W1; Wt = T1; N = 1024; K = 1024; tix = id - 3072; }
  else if (id < 8192) { W = W2; Wt = T2; N = 4096; K = 1024; tix = id - 4096; }
  else                { W = W3; Wt = T3; N = 1024; K = 4096; tix = id - 8192; }
  int nx = N / 32;
  int n0 = (tix % nx) * 32, k0 = (tix / nx) * 32;
  int tx = threadIdx.x & 31, ty = threadIdx.x >> 5;
#pragma unroll
  for (int i = 0; i < 4; i++)
    t[ty + 8 * i][tx] = W[(size_t)(k0 + ty + 8 * i) * N + n0 + tx];
  __syncthreads();
#pragma unroll
  for (int i = 0; i < 4; i++)
    Wt[(size_t)(n0 + ty + 8 * i) * K + k0 + tx] = f2bf(t[tx][ty + 8 * i]);
}

// -------- fused: x1 = x + bias + sum(4 partials) (f32), then h2 = LN2(x1) ----
__global__ __launch_bounds__(256) void reduce_ln_kernel(const float* __restrict__ x,
                                                        const float* __restrict__ bias,
                                                        const short* __restrict__ parts,
                                                        const float* __restrict__ g,
                                                        const float* __restrict__ be,
                                                        float* __restrict__ x1,
                                                        short* __restrict__ h2) {
  int row = blockIdx.x, tid = threadIdx.x;
  size_t base = (size_t)row * Dd + tid * 4;
  float4 v = *(const float4*)(x + base);
  float4 bv = ((const float4*)bias)[tid];
  v.x += bv.x; v.y += bv.y; v.z += bv.z; v.w += bv.w;
#pragma unroll
  for (int s = 0; s < 4; s++) {
    short4v p = *(const short4v*)(parts + (size_t)s * 4096 * Dd + base);
    v.x += bf2f(p.x); v.y += bf2f(p.y); v.z += bf2f(p.z); v.w += bf2f(p.w);
  }
  *(float4*)(x1 + base) = v;
  float s = v.x + v.y + v.z + v.w;
  float q = v.x * v.x + v.y * v.y + v.z * v.z + v.w * v.w;
#pragma unroll
  for (int off = 1; off < 64; off <<= 1) {
    s += __shfl_xor(s, off);
    q += __shfl_xor(q, off);
  }
  __shared__ float as_[4], aq_[4];
  int w = tid >> 6;
  if ((tid & 63) == 0) { as_[w] = s; aq_[w] = q; }
  __syncthreads();
  s = as_[0] + as_[1] + as_[2] + as_[3];
  q = aq_[0] + aq_[1] + aq_[2] + aq_[3];
  float mu = s * (1.0f / Dd);
  float var = q * (1.0f / Dd) - mu * mu;
  float rstd = rsqrtf(var + 1e-5f);
  float4 gv = ((const float4*)g)[tid], b2 = ((const float4*)be)[tid];
  short4v o;
  o.x = f2bf((v.x - mu) * rstd * gv.x + b2.x);
  o.y = f2bf((v.y - mu) * rstd * gv.y + b2.y);
  o.z = f2bf((v.z - mu) * rstd * gv.z + b2.z);
  o.w = f2bf((v.w - mu) * rstd * gv.w + b2.w);
  *(short4v*)(h2 + base) = o;
}

// ---------------- final reduce: dst = src + bias + sum(4 bf16 partials) ------
__global__ __launch_bounds__(256) void reduce_kernel(const float* __restrict__ src,
                                                     const float* __restrict__ bias,
                                                     const short* __restrict__ parts,
                                                     float* __restrict__ dst) {
  int row = blockIdx.x, tid = threadIdx.x;
  size_t base = (size_t)row * Dd + tid * 4;
  float4 v = *(const float4*)(src + base);
  float4 bv = ((const float4*)bias)[tid];
  v.x += bv.x; v.y += bv.y; v.z += bv.z; v.w += bv.w;
#pragma unroll
  for (int s = 0; s < 4; s++) {
    short4v p = *(const short4v*)(parts + (size_t)s * 4096 * Dd + base);
    v.x += bf2f(p.x); v.y += bf2f(p.y); v.z += bf2f(p.z); v.w += bf2f(p.w);
  }
  *(float4*)(dst + base) = v;
}

// ---------------- 256x256 bf16 MFMA GEMM, 8 waves, 4-phase/K-tile, ------------
// double-buffered 128KiB LDS, counted vmcnt (never 0 in steady state),
// raw s_barrier (no vmcnt drain), setprio around MFMA clusters.
// Staging pipeline: B(t+1) issued at ph1 of tile t; A(t+2) at ph4 of tile t;
// single s_waitcnt vmcnt(4) per tile drains exactly A(t+1)+B(t+1).
// MODE 2: bf16 out = gelu(acc+bias); MODE 3: bf16 partial at outp + zp*M*N;
// MODE 4: bf16 out = acc+bias, plus transposed Vt write for cols >= 2048.
template <int MODE>
__device__ __forceinline__ void gemm256(const short* __restrict__ A,
                                        const short* __restrict__ Bt,
                                        const float* __restrict__ bias,
                                        void* __restrict__ outp,
                                        short* __restrict__ vtp,
                                        int M, int N, int K,
                                        int m0, int n0, int zp,
                                        int ks, int nt, char* smem) {
  const int tid = threadIdx.x;
  const int wid = tid >> 6, lane = tid & 63;
  const int wm = wid >> 2, wn = wid & 3;      // 2 x 4 wave grid
  const int fr = lane & 15, g = lane >> 4;
  const int r0 = tid >> 3, sl = tid & 7;
  const int gcs = sl ^ (r0 & 7);              // pre-swizzled global slot
  // LDS dest is linear tid*16 per wave-uniform base (gl_lds constraint).
  const int lOff = r0 * 128 + sl * 16;

  const short* gA = A + (size_t)(m0 + r0) * K + ks + gcs * 8;
  const short* gB = Bt + (size_t)(n0 + r0) * K + ks + gcs * 8;

  auto stageA = [&](int t) {
    char* la = smem + (t & 1) * 65536 + lOff;
    const short* ga = gA + t * 64;
#pragma unroll
    for (int i = 0; i < 4; i++)
      gl_lds16(ga + (size_t)(64 * i) * K, la + i * 8192);
  };
  auto stageB = [&](int t) {
    char* lb = smem + (t & 1) * 65536 + 32768 + lOff;
    const short* gb = gB + t * 64;
#pragma unroll
    for (int i = 0; i < 4; i++)
      gl_lds16(gb + (size_t)(64 * i) * K, lb + i * 8192);
  };

  const int aoff0 = (g ^ (fr & 7)) * 16;
  const int aoff1 = ((g + 4) ^ (fr & 7)) * 16;
  const int arow = (wm * 128 + fr) * 128;  // byte offset of wave's A rows
  const int brow = (wn * 64 + fr) * 128;   // byte offset of wave's B rows

  float4v acc[8][4] = {};
  short8 a[4][2], b[4][2];

  // prologue: A(0), B(0), A(1); leave A(1) in flight
  stageA(0);
  stageB(0);
  if (nt > 1) {
    stageA(1);
    asm volatile("s_waitcnt vmcnt(4)" ::: "memory");
  } else {
    asm volatile("s_waitcnt vmcnt(0)" ::: "memory");
  }
  __builtin_amdgcn_s_barrier();

  for (int t = 0; t < nt; t++) {
    char* lA = smem + (t & 1) * 65536;
    char* lB = lA + 32768;
    // ---- phase 1: read A rows 0-63 + B cols 0-31; issue B(t+1) ----
#pragma unroll
    for (int i = 0; i < 4; i++) {
      a[i][0] = *(const short8*)(lA + arow + i * 2048 + aoff0);
      a[i][1] = *(const short8*)(lA + arow + i * 2048 + aoff1);
    }
    if (t + 1 < nt) stageB(t + 1);
#pragma unroll
    for (int j = 0; j < 2; j++) {
      b[j][0] = *(const short8*)(lB + brow + j * 2048 + aoff0);
      b[j][1] = *(const short8*)(lB + brow + j * 2048 + aoff1);
    }
    __builtin_amdgcn_s_barrier();
    asm volatile("s_waitcnt lgkmcnt(0)" ::: "memory");
    __builtin_amdgcn_s_setprio(1);
#pragma unroll
    for (int i = 0; i < 4; i++)
#pragma unroll
      for (int j = 0; j < 2; j++) {
        acc[i][j] = MFMA(a[i][0], b[j][0], acc[i][j]);
        acc[i][j] = MFMA(a[i][1], b[j][1], acc[i][j]);
      }
    __builtin_amdgcn_s_setprio(0);
    __builtin_amdgcn_s_barrier();
    // ---- phase 2: read B cols 32-63 ----
#pragma unroll
    for (int j = 2; j < 4; j++) {
      b[j][0] = *(const short8*)(lB + brow + j * 2048 + aoff0);
      b[j][1] = *(const short8*)(lB + brow + j * 2048 + aoff1);
    }
    __builtin_amdgcn_s_barrier();
    asm volatile("s_waitcnt lgkmcnt(0)" ::: "memory");
    __builtin_amdgcn_s_setprio(1);
#pragma unroll
    for (int i = 0; i < 4; i++)
#pragma unroll
      for (int j = 2; j < 4; j++) {
        acc[i][j] = MFMA(a[i][0], b[j][0], acc[i][j]);
        acc[i][j] = MFMA(a[i][1], b[j][1], acc[i][j]);
      }
    __builtin_amdgcn_s_setprio(0);
    __builtin_amdgcn_s_barrier();
    // ---- phase 3: read A rows 64-127 (overwrite a regs) ----
#pragma unroll
    for (int i = 0; i < 4; i++) {
      a[i][0] = *(const short8*)(lA + arow + 8192 + i * 2048 + aoff0);
      a[i][1] = *(const short8*)(lA + arow + 8192 + i * 2048 + aoff1);
    }
    __builtin_amdgcn_s_barrier();
    asm volatile("s_waitcnt lgkmcnt(0)" ::: "memory");
    __builtin_amdgcn_s_setprio(1);
#pragma unroll
    for (int i = 0; i < 4; i++)
#pragma unroll
      for (int j = 2; j < 4; j++) {
        acc[4 + i][j] = MFMA(a[i][0], b[j][0], acc[4 + i][j]);
        acc[4 + i][j] = MFMA(a[i][1], b[j][1], acc[4 + i][j]);
      }
    __builtin_amdgcn_s_setprio(0);
    __builtin_amdgcn_s_barrier();
    // ---- phase 4: issue A(t+2) (Acur fully read after ph3 barrier), ----
    // ---- MFMA remaining quadrant, counted vmcnt, tile barrier ----
    if (t + 2 < nt) stageA(t + 2);
    __builtin_amdgcn_s_setprio(1);
#pragma unroll
    for (int i = 0; i < 4; i++)
#pragma unroll
      for (int j = 0; j < 2; j++) {
        acc[4 + i][j] = MFMA(a[i][0], b[j][0], acc[4 + i][j]);
        acc[4 + i][j] = MFMA(a[i][1], b[j][1], acc[4 + i][j]);
      }
    __builtin_amdgcn_s_setprio(0);
    if (t + 1 < nt) {
      if (t + 2 < nt)
        asm volatile("s_waitcnt vmcnt(4)" ::: "memory");  // keep A(t+2) in flight
      else
        asm volatile("s_waitcnt vmcnt(0)" ::: "memory");  // tail drain
      __builtin_amdgcn_s_barrier();
    }
  }

  // ---- epilogue ----
  const int crow = g * 4;
#pragma unroll
  for (int i = 0; i < 8; i++) {
#pragma unroll
    for (int j = 0; j < 4; j++) {
      int col = n0 + wn * 64 + j * 16 + fr;
      float bcol = (MODE == 3) ? 0.f : bias[col];
      short sh[4];
#pragma unroll
      for (int r = 0; r < 4; r++) {
        int row = m0 + wm * 128 + i * 16 + crow + r;
        float v = acc[i][j][r] + bcol;
        if (MODE == 4) {
          sh[r] = f2bf(v);
          ((short*)outp)[(size_t)row * N + col] = sh[r];
        } else if (MODE == 2) {
          float y = 0.79788456f * (v + 0.044715f * v * v * v);
          float e = __builtin_amdgcn_exp2f(y * 2.885390082f);
          float th = 1.0f - 2.0f * __builtin_amdgcn_rcpf(e + 1.0f);
          v = 0.5f * v * (1.0f + th);
          ((short*)outp)[(size_t)row * N + col] = f2bf(v);
        } else {
          short* pp = (short*)outp + (size_t)zp * M * N;
          pp[(size_t)row * N + col] = f2bf(v);
        }
      }
      if (MODE == 4 && col >= 2048) {
        // transposed V write: Vt[(bh*64+d)*Ss + s], 4 consecutive s per lane
        int hd = col - 2048;
        int rbase = m0 + wm * 128 + i * 16 + crow;
        int bq = rbase >> 11, sb = rbase & 2047;
        int bh = bq * 16 + (hd >> 6), d = hd & 63;
        short4v pk;
        pk.x = sh[0]; pk.y = sh[1]; pk.z = sh[2]; pk.w = sh[3];
        *(short4v*)(vtp + (size_t)(bh * 64 + d) * Ss + sb) = pk;
      }
    }
  }
}

// ---------------- qkv GEMM (+fused V transpose): 192 blocks, 4m x 6n/XCD -----
__global__ __launch_bounds__(512, 2) void k_gemm_qkv(const short* __restrict__ A,
                                                     const short* __restrict__ Bt,
                                                     const float* __restrict__ bias,
                                                     short* __restrict__ o,
                                                     short* __restrict__ Vt) {
  extern __shared__ char smem[];
  int xcd = blockIdx.x & 7, u = blockIdx.x >> 3;
  int m0 = ((xcd >> 1) * 4 + u / 6) * 256;
  int n0 = ((xcd & 1) * 6 + u % 6) * 256;
  gemm256<4>(A, Bt, bias, o, Vt, 4096, 3072, 1024, m0, n0, 0, 0, 16, smem);
}

// ---------------- fc GEMM+GELU: 256 blocks, 4m x 8n per XCD ------------------
__global__ __launch_bounds__(512, 2) void k_gemm_fc(const short* __restrict__ A,
                                                    const short* __restrict__ Bt,
                                                    const float* __restrict__ bias,
                                                    short* __restrict__ o) {
  extern __shared__ char smem[];
  int xcd = blockIdx.x & 7, u = blockIdx.x >> 3;
  int m0 = ((xcd >> 1) * 4 + (u >> 3)) * 256;
  int n0 = ((xcd & 1) * 8 + (u & 7)) * 256;
  gemm256<2>(A, Bt, bias, o, nullptr, 4096, 4096, 1024, m0, n0, 0, 0, 16, smem);
}

// ---------------- wo projection: 256 blocks, split-K=4 -----------------------
__global__ __launch_bounds__(512, 2) void k_gemm_wo(const short* __restrict__ A,
                                                    const short* __restrict__ Bt,
                                                    short* __restrict__ parts) {
  extern __shared__ char smem[];
  int xcd = blockIdx.x & 7, u = blockIdx.x >> 3;
  int z = u >> 3;
  int m0 = (xcd * 2 + ((u >> 2) & 1)) * 256;
  int n0 = (u & 3) * 256;
  gemm256<3>(A, Bt, nullptr, parts, nullptr, 4096, 1024, 1024, m0, n0, z,
             z * 256, 4, smem);
}

// ---------------- pr projection: 256 blocks, split-K=4 -----------------------
__global__ __launch_bounds__(512, 2) void k_gemm_pr(const short* __restrict__ A,
                                                    const short* __restrict__ Bt,
                                                    short* __restrict__ parts) {
  extern __shared__ char smem[];
  int xcd = blockIdx.x & 7, u = blockIdx.x >> 3;
  int z = u >> 3;
  int m0 = (xcd * 2 + ((u >> 2) & 1)) * 256;
  int n0 = (u & 3) * 256;
  gemm256<3>(A, Bt, nullptr, parts, nullptr, 4096, 1024, 4096, m0, n0, z,
             z * 1024, 16, smem);
}

// ---------------- flash attention, early-issue prefetch staging --------------
__global__ __launch_bounds__(256) void flash_kernel(const short* __restrict__ qkv,
                                                    const short* __restrict__ Vt,
                                                    short* __restrict__ att) {
  __shared__ __align__(16) short Ks[4096];
  __shared__ __align__(16) short Vs[4096];
  __shared__ __align__(16) short P[4][16 * 72];
  const int w = threadIdx.x >> 6, lane = threadIdx.x & 63;
  const int qb = 31 - (blockIdx.x >> 5);
  const int bh = blockIdx.x & 31;
  const int b = bh >> 4, h = bh & 15;
  const int qbase = qb * 64 + w * 16;
  const int q = lane & 15;
  const int g = lane >> 4;
  const int fk = g * 8;
  short* Pw = &P[w][0];

  const int L0 = w * 64 + lane, L1 = L0 + 256;
  const int r0 = L0 >> 3, c0 = (L0 & 7) ^ (r0 & 7);
  const int r1 = L1 >> 3, c1 = (L1 & 7) ^ (r1 & 7);
  const short* kg0 = qkv + (size_t)(b * Ss + r0) * 3072 + 1024 + h * 64 + c0 * 8;
  const short* kg1 = qkv + (size_t)(b * Ss + r1) * 3072 + 1024 + h * 64 + c1 * 8;
  const short* vg0 = Vt + (size_t)(bh * 64 + r0) * Ss + c0 * 8;
  const short* vg1 = Vt + (size_t)(bh * 64 + r1) * Ss + c1 * 8;

  short8 qf[2];
  {
    const short* qrow = qkv + (size_t)(b * Ss + qbase + q) * 3072 + h * 64;
    qf[0] = *(const short8*)(qrow + fk);
    qf[1] = *(const short8*)(qrow + 32 + fk);
  }
  float4v o[4] = {};
  float l_i = 0.f;
  const float sc = 0.125f * 1.44269504088896f;
  const int nkt = qb + 1;

  // prologue staging for kt = 0
  gl_lds16(kg0, Ks + L0 * 8);
  gl_lds16(kg1, Ks + L1 * 8);
  gl_lds16(vg0, Vs + L0 * 8);
  gl_lds16(vg1, Vs + L1 * 8);

  for (int kt = 0; kt < nkt; kt++) {
    const int kbase = kt * 64;
    __syncthreads();  // staging for kt complete

    short8 kf[4][2], vf[4][2];
#pragma unroll
    for (int t = 0; t < 4; t++) {
      const int row = 16 * t + q;
      const int sw = (g ^ (row & 7)) * 8;
      kf[t][0] = *(const short8*)(Ks + row * 64 + sw);
      kf[t][1] = *(const short8*)(Ks + row * 64 + (sw ^ 32));
      vf[t][0] = *(const short8*)(Vs + row * 64 + sw);
      vf[t][1] = *(const short8*)(Vs + row * 64 + (sw ^ 32));
    }
    __syncthreads();  // all waves consumed Ks/Vs
    if (kt + 1 < nkt) {
      const size_t nb = (size_t)(kbase + 64);
      gl_lds16(kg0 + nb * 3072, Ks + L0 * 8);
      gl_lds16(kg1 + nb * 3072, Ks + L1 * 8);
      gl_lds16(vg0 + nb, Vs + L0 * 8);
      gl_lds16(vg1 + nb, Vs + L1 * 8);
    }

    float4v s[4] = {};
#pragma unroll
    for (int t = 0; t < 4; t++) {
      s[t] = MFMA(kf[t][0], qf[0], s[t]);
      s[t] = MFMA(kf[t][1], qf[1], s[t]);
    }
    const bool maskt = (kbase + 63 > qbase);
    const int qlim = qbase + q - kbase;
    float p[4][4];
    float rs = 0.f;
#pragma unroll
    for (int t = 0; t < 4; t++) {
#pragma unroll
      for (int r = 0; r < 4; r++) {
        float v = s[t][r] * sc;
        if (maskt && (16 * t + 4 * g + r > qlim)) v = -3.0e38f;
        float e = __builtin_amdgcn_exp2f(v);
        p[t][r] = e;
        rs += e;
      }
    }
    rs += __shfl_xor(rs, 16);
    rs += __shfl_xor(rs, 32);
    l_i += rs;
#pragma unroll
    for (int t = 0; t < 4; t++) {
      unsigned lo = (unsigned)(unsigned short)f2bf(p[t][0]) |
                    ((unsigned)(unsigned short)f2bf(p[t][1]) << 16);
      unsigned hi = (unsigned)(unsigned short)f2bf(p[t][2]) |
                    ((unsigned)(unsigned short)f2bf(p[t][3]) << 16);
      uint2 u; u.x = lo; u.y = hi;
      *(uint2*)(Pw + q * 72 + 16 * t + 4 * g) = u;
    }
    asm volatile("s_waitcnt lgkmcnt(0)" ::: "memory");
    short8 pb0 = *(const short8*)(Pw + q * 72 + fk);
    short8 pb1 = *(const short8*)(Pw + q * 72 + 32 + fk);
#pragma unroll
    for (int t = 0; t < 4; t++) {
      o[t] = MFMA(vf[t][0], pb0, o[t]);
      o[t] = MFMA(vf[t][1], pb1, o[t]);
    }
  }
  const float inv = 1.0f / l_i;
  const int orow = b * Ss + qbase + q;
#pragma unroll
  for (int t = 0; t < 4; t++) {
    short4v ov;
    ov.x = f2bf(o[t][0] * inv);
    ov.y = f2bf(o[t][1] * inv);
    ov.z = f2bf(o[t][2] * inv);
    ov.w = f2bf(o[t][3] * inv);
    *(short4v*)(att + (size_t)orow * Dd + h * 64 + 16 * t + 4 * g) = ov;
  }
}

extern "C" void kernel_launch(void* const* d_in, const int* in_sizes, int n_in,
                              void* d_out, int out_size, void* d_ws, size_t ws_size,
                              hipStream_t stream) {
  const float* x    = (const float*)d_in[0];
  const float* Wqkv = (const float*)d_in[1];
  const float* bqkv = (const float*)d_in[2];
  const float* Wo   = (const float*)d_in[3];
  const float* bo   = (const float*)d_in[4];
  const float* Wfc  = (const float*)d_in[5];
  const float* bfc  = (const float*)d_in[6];
  const float* Wpr  = (const float*)d_in[7];
  const float* bpr  = (const float*)d_in[8];
  const float* g1   = (const float*)d_in[9];
  const float* be1  = (const float*)d_in[10];
  const float* g2   = (const float*)d_in[11];
  const float* be2  = (const float*)d_in[12];

  char* ws = (char*)d_ws;
  const size_t MB = 1024 * 1024;
  short* h1     = (short*)(ws + 0);        // [0,8)
  short* qkvb   = (short*)(ws + 8 * MB);   // [8,32)
  short* partWo = (short*)(ws + 0);        // [0,32), after flash (h1/qkvb dead)
  short* partPr = (short*)(ws + 0);        // [0,32), after fc (partWo dead)
  short* Vt     = (short*)(ws + 32 * MB);  // [32,40)
  short* att    = (short*)(ws + 40 * MB);  // [40,48)
  float* x1     = (float*)(ws + 48 * MB);  // [48,64)
  short* h2     = (short*)(ws + 64 * MB);  // [64,72)
  short* geluo  = (short*)(ws + 72 * MB);  // [72,104)
  short* WtQkv  = (short*)(ws + 104 * MB);
  short* WtO    = (short*)(ws + 110 * MB);
  short* WtFc   = (short*)(ws + 112 * MB);
  short* WtPr   = (short*)(ws + 120 * MB);

  prep_kernel<<<16384, 256, 0, stream>>>(Wqkv, WtQkv, Wo, WtO, Wfc, WtFc,
                                         Wpr, WtPr, x, g1, be1, h1);
  k_gemm_qkv<<<192, 512, 131072, stream>>>(h1, WtQkv, bqkv, qkvb, Vt);
  flash_kernel<<<1024, 256, 0, stream>>>(qkvb, Vt, att);
  k_gemm_wo<<<256, 512, 131072, stream>>>(att, WtO, partWo);
  reduce_ln_kernel<<<4096, 256, 0, stream>>>(x, bo, partWo, g2, be2, x1, h2);
  k_gemm_fc<<<256, 512, 131072, stream>>>(h2, WtFc, bfc, geluo);
  k_gemm_pr<<<256, 512, 131072, stream>>>(geluo, WtPr, partPr);
  reduce_kernel<<<4096, 256, 0, stream>>>(x1, bpr, partPr, (float*)d_out);
}

// Round 3
// 303.644 us; speedup vs baseline: 1.0258x; 1.0258x over previous
//
#include <hip/hip_runtime.h>
#include <cstdint>
#include <cstddef>

#define Bb 2
#define Ss 2048
#define Dd 1024
#define Hh 16

typedef __attribute__((ext_vector_type(8))) short short8;
typedef __attribute__((ext_vector_type(4))) short short4v;
typedef __attribute__((ext_vector_type(4))) float float4v;

__device__ inline short f2bf(float f) {
  unsigned u = __builtin_bit_cast(unsigned, f);
  u = (u + 0x7fffu + ((u >> 16) & 1u)) >> 16;
  return (short)u;
}

__device__ inline float bf2f(short s) {
  unsigned u = ((unsigned)(unsigned short)s) << 16;
  return __builtin_bit_cast(float, u);
}

__device__ inline void gl_lds16(const void* g, void* l) {
  __builtin_amdgcn_global_load_lds(
      (__attribute__((address_space(1))) void*)(void*)(g),
      (__attribute__((address_space(3))) void*)(l), 16, 0, 0);
}

#define MFMA(a, b, c) __builtin_amdgcn_mfma_f32_16x16x32_bf16((a), (b), (c), 0, 0, 0)
#define BAR() __builtin_amdgcn_s_barrier()
#define LGKM0() asm volatile("s_waitcnt lgkmcnt(0)" ::: "memory")
#define VMC(n) asm volatile("s_waitcnt vmcnt(" #n ")" ::: "memory")

// ---------------- LN row body (f32 in -> bf16 out) ----------------
__device__ __forceinline__ void ln_row(const float* __restrict__ x,
                                       const float* __restrict__ g,
                                       const float* __restrict__ be,
                                       short* __restrict__ out, int row,
                                       float* red) {
  int tid = threadIdx.x;
  const float4* xr = (const float4*)(x + (size_t)row * Dd);
  float4 v = xr[tid];
  float s = v.x + v.y + v.z + v.w;
  float q = v.x * v.x + v.y * v.y + v.z * v.z + v.w * v.w;
#pragma unroll
  for (int off = 1; off < 64; off <<= 1) {
    s += __shfl_xor(s, off);
    q += __shfl_xor(q, off);
  }
  int w = tid >> 6;
  if ((tid & 63) == 0) { red[w] = s; red[4 + w] = q; }
  __syncthreads();
  s = red[0] + red[1] + red[2] + red[3];
  q = red[4] + red[5] + red[6] + red[7];
  float mu = s * (1.0f / Dd);
  float var = q * (1.0f / Dd) - mu * mu;
  float rstd = rsqrtf(var + 1e-5f);
  float4 gv = ((const float4*)g)[tid], bv = ((const float4*)be)[tid];
  short4v o;
  o.x = f2bf((v.x - mu) * rstd * gv.x + bv.x);
  o.y = f2bf((v.y - mu) * rstd * gv.y + bv.y);
  o.z = f2bf((v.z - mu) * rstd * gv.z + bv.z);
  o.w = f2bf((v.w - mu) * rstd * gv.w + bv.w);
  *(short4v*)(out + (size_t)row * Dd + tid * 4) = o;
}

// ---------------- prep: 4 weight transposes + LN1, by block range ------------
__global__ __launch_bounds__(256) void prep_kernel(
    const float* __restrict__ W0, short* __restrict__ T0,
    const float* __restrict__ W1, short* __restrict__ T1,
    const float* __restrict__ W2, short* __restrict__ T2,
    const float* __restrict__ W3, short* __restrict__ T3,
    const float* __restrict__ x, const float* __restrict__ g1,
    const float* __restrict__ be1, short* __restrict__ h1) {
  __shared__ __align__(16) float t[32][33];
  int id = blockIdx.x;
  if (id >= 12288) {
    ln_row(x, g1, be1, h1, id - 12288, &t[0][0]);
    return;
  }
  const float* W; short* Wt; int N, K, tix;
  if (id < 3072)      { W = W0; Wt = T0; N = 3072; K = 1024; tix = id; }
  else if (id < 4096) { W = W1; Wt = T1; N = 1024; K = 1024; tix = id - 3072; }
  else if (id < 8192) { W = W2; Wt = T2; N = 4096; K = 1024; tix = id - 4096; }
  else                { W = W3; Wt = T3; N = 1024; K = 4096; tix = id - 8192; }
  int nx = N / 32;
  int n0 = (tix % nx) * 32, k0 = (tix / nx) * 32;
  int tx = threadIdx.x & 31, ty = threadIdx.x >> 5;
#pragma unroll
  for (int i = 0; i < 4; i++)
    t[ty + 8 * i][tx] = W[(size_t)(k0 + ty + 8 * i) * N + n0 + tx];
  __syncthreads();
#pragma unroll
  for (int i = 0; i < 4; i++)
    Wt[(size_t)(n0 + ty + 8 * i) * K + k0 + tx] = f2bf(t[tx][ty + 8 * i]);
}

// -------- fused: x1 = x + bias + sum(4 partials) (f32), then h2 = LN2(x1) ----
__global__ __launch_bounds__(256) void reduce_ln_kernel(const float* __restrict__ x,
                                                        const float* __restrict__ bias,
                                                        const short* __restrict__ parts,
                                                        const float* __restrict__ g,
                                                        const float* __restrict__ be,
                                                        float* __restrict__ x1,
                                                        short* __restrict__ h2) {
  int row = blockIdx.x, tid = threadIdx.x;
  size_t base = (size_t)row * Dd + tid * 4;
  float4 v = *(const float4*)(x + base);
  float4 bv = ((const float4*)bias)[tid];
  v.x += bv.x; v.y += bv.y; v.z += bv.z; v.w += bv.w;
#pragma unroll
  for (int s = 0; s < 4; s++) {
    short4v p = *(const short4v*)(parts + (size_t)s * 4096 * Dd + base);
    v.x += bf2f(p.x); v.y += bf2f(p.y); v.z += bf2f(p.z); v.w += bf2f(p.w);
  }
  *(float4*)(x1 + base) = v;
  float s = v.x + v.y + v.z + v.w;
  float q = v.x * v.x + v.y * v.y + v.z * v.z + v.w * v.w;
#pragma unroll
  for (int off = 1; off < 64; off <<= 1) {
    s += __shfl_xor(s, off);
    q += __shfl_xor(q, off);
  }
  __shared__ float as_[4], aq_[4];
  int w = tid >> 6;
  if ((tid & 63) == 0) { as_[w] = s; aq_[w] = q; }
  __syncthreads();
  s = as_[0] + as_[1] + as_[2] + as_[3];
  q = aq_[0] + aq_[1] + aq_[2] + aq_[3];
  float mu = s * (1.0f / Dd);
  float var = q * (1.0f / Dd) - mu * mu;
  float rstd = rsqrtf(var + 1e-5f);
  float4 gv = ((const float4*)g)[tid], b2 = ((const float4*)be)[tid];
  short4v o;
  o.x = f2bf((v.x - mu) * rstd * gv.x + b2.x);
  o.y = f2bf((v.y - mu) * rstd * gv.y + b2.y);
  o.z = f2bf((v.z - mu) * rstd * gv.z + b2.z);
  o.w = f2bf((v.w - mu) * rstd * gv.w + b2.w);
  *(short4v*)(h2 + base) = o;
}

// ---------------- final reduce: dst = src + bias + sum(4 bf16 partials) ------
__global__ __launch_bounds__(256) void reduce_kernel(const float* __restrict__ src,
                                                     const float* __restrict__ bias,
                                                     const short* __restrict__ parts,
                                                     float* __restrict__ dst) {
  int row = blockIdx.x, tid = threadIdx.x;
  size_t base = (size_t)row * Dd + tid * 4;
  float4 v = *(const float4*)(src + base);
  float4 bv = ((const float4*)bias)[tid];
  v.x += bv.x; v.y += bv.y; v.z += bv.z; v.w += bv.w;
#pragma unroll
  for (int s = 0; s < 4; s++) {
    short4v p = *(const short4v*)(parts + (size_t)s * 4096 * Dd + base);
    v.x += bf2f(p.x); v.y += bf2f(p.y); v.z += bf2f(p.z); v.w += bf2f(p.w);
  }
  *(float4*)(dst + base) = v;
}

// ---------------- 256x256 bf16 MFMA GEMM, 8 waves, m201 8-phase schedule -----
// 2 K-tiles per iteration (static buffers), 1 half-tile stage (2 gl_lds)
// per phase in consumption order, vmcnt(6) at ph4/ph8 only (3 half-tiles in
// flight across barriers), raw s_barrier, setprio around MFMA clusters.
// A-halves: 64-row chunks {0-63,128-191} / {64-127,192-255} (per-wave regions).
// B-halves: interleaved 32-row chunks matching per-phase consumption.
// MODE 2: bf16 out = gelu(acc+bias); MODE 3: bf16 partial at outp + zp*M*N;
// MODE 4: bf16 out = acc+bias, plus transposed Vt write for cols >= 2048.
template <int MODE>
__device__ __forceinline__ void gemm256(const short* __restrict__ A,
                                        const short* __restrict__ Bt,
                                        const float* __restrict__ bias,
                                        void* __restrict__ outp,
                                        short* __restrict__ vtp,
                                        int M, int N, int K,
                                        int m0, int n0, int zp,
                                        int ks, int nt, char* smem) {
  const int tid = threadIdx.x;
  const int wid = tid >> 6, lane = tid & 63;
  const int wm = wid >> 2, wn = wid & 3;      // 2 x 4 wave grid
  const int fr = lane & 15, g = lane >> 4;
  const int rA = tid >> 3, sl = tid & 7;
  const int gcs = sl ^ (rA & 7);              // pre-swizzled global k-slot
  const int lOff = rA * 128 + sl * 16;        // linear LDS offset (A chunks)
  const int rB = (wid >> 2) * 64 + (wid & 3) * 8 + (lane >> 3);  // B chunk row
  const int lOffB = rB * 128 + sl * 16;       // (rB&7)==(rA&7) -> same gcs

  const short* gA = A + (size_t)(m0 + rA) * K + ks + gcs * 8;
  const short* gB = Bt + (size_t)(n0 + rB) * K + ks + gcs * 8;

  auto sA = [&](int bo, int roff, int t) {
    gl_lds16(gA + (size_t)roff * K + (size_t)t * 64, smem + bo + roff * 128 + lOff);
  };
  auto sB = [&](int bo, int roff, int t) {
    gl_lds16(gB + (size_t)roff * K + (size_t)t * 64,
             smem + bo + 32768 + roff * 128 + lOffB);
  };
  // half-tile stages (2 loads each)
  auto AH0 = [&](int bo, int t) { sA(bo, 0, t); sA(bo, 128, t); };
  auto AH1 = [&](int bo, int t) { sA(bo, 64, t); sA(bo, 192, t); };
  auto BH0 = [&](int bo, int t) { sB(bo, 0, t); sB(bo, 128, t); };
  auto BH1 = [&](int bo, int t) { sB(bo, 32, t); sB(bo, 160, t); };

  const int aoff0 = (g ^ (fr & 7)) * 16;
  const int aoff1 = ((g + 4) ^ (fr & 7)) * 16;
  const int arow = (wm * 128 + fr) * 128;  // byte offset of wave's A rows
  const int brow = (wn * 64 + fr) * 128;   // byte offset of wave's B rows

  float4v acc[8][4] = {};
  short8 a[4][2], b[4][2];

  auto RA = [&](int bo, int half) {  // wave-local A rows half*64..+63
    const char* p = smem + bo + arow + half * 8192;
#pragma unroll
    for (int i = 0; i < 4; i++) {
      a[i][0] = *(const short8*)(p + i * 2048 + aoff0);
      a[i][1] = *(const short8*)(p + i * 2048 + aoff1);
    }
  };
  auto RB = [&](int bo, int jh) {  // wave-local B cols jh*32..+31
    const char* p = smem + bo + 32768 + brow + jh * 4096;
#pragma unroll
    for (int j = 0; j < 2; j++) {
      b[2 * jh + j][0] = *(const short8*)(p + j * 2048 + aoff0);
      b[2 * jh + j][1] = *(const short8*)(p + j * 2048 + aoff1);
    }
  };
  auto MM = [&](int qi, int qj) {  // 16 MFMA: acc rows qi*4.., cols qj*2..
    __builtin_amdgcn_s_setprio(1);
#pragma unroll
    for (int i = 0; i < 4; i++)
#pragma unroll
      for (int j = 0; j < 2; j++) {
        const int jj = 2 * qj + j;
        acc[4 * qi + i][jj] = MFMA(a[i][0], b[jj][0], acc[4 * qi + i][jj]);
        acc[4 * qi + i][jj] = MFMA(a[i][1], b[jj][1], acc[4 * qi + i][jj]);
      }
    __builtin_amdgcn_s_setprio(0);
  };

  // prologue: T0 fully, T1 three halves; drain T0 (vmcnt leaves 6 loads)
  AH0(0, 0); BH0(0, 0); BH1(0, 0); AH1(0, 0);
  AH0(65536, 1); BH0(65536, 1); BH1(65536, 1);
  VMC(6);
  BAR();

  const int nit = nt / 2 - 1;
  for (int it = 0; it < nit; ++it) {
    const int t1 = 2 * it + 1, t2 = 2 * it + 2, t3 = 2 * it + 3;
    // ph1 (buf0): A0-63 + B0-31 reads; stage T1.Ah1
    RA(0, 0); RB(0, 0); AH1(65536, t1);
    BAR(); LGKM0(); MM(0, 0); BAR();
    // ph2: B32-63 reads; stage T2.Ah0
    RB(0, 1); AH0(0, t2);
    BAR(); LGKM0(); MM(0, 1); BAR();
    // ph3: A64-127 reads; stage T2.Bh0
    RA(0, 1); BH0(0, t2);
    BAR(); LGKM0(); MM(1, 1); BAR();
    // ph4: stage T2.Bh1; MFMA (regs only); drain T1 halves (keep 3 in flight)
    BH1(0, t2);
    MM(1, 0);
    VMC(6); BAR();
    // ph5 (buf1): reads; stage T2.Ah1
    RA(65536, 0); RB(65536, 0); AH1(0, t2);
    BAR(); LGKM0(); MM(0, 0); BAR();
    // ph6: stage T3.Ah0
    RB(65536, 1); AH0(65536, t3);
    BAR(); LGKM0(); MM(0, 1); BAR();
    // ph7: stage T3.Bh0
    RA(65536, 1); BH0(65536, t3);
    BAR(); LGKM0(); MM(1, 1); BAR();
    // ph8: stage T3.Bh1; MFMA; drain T2 halves
    BH1(65536, t3);
    MM(1, 0);
    VMC(6); BAR();
  }
  // tail: tiles nt-2 (buf0), nt-1 (buf1)
  RA(0, 0); RB(0, 0); AH1(65536, nt - 1);
  BAR(); LGKM0(); MM(0, 0); BAR();
  RB(0, 1);
  BAR(); LGKM0(); MM(0, 1); BAR();
  RA(0, 1);
  BAR(); LGKM0(); MM(1, 1); BAR();
  MM(1, 0);
  VMC(0); BAR();
  RA(65536, 0); RB(65536, 0);
  BAR(); LGKM0(); MM(0, 0); BAR();
  RB(65536, 1);
  BAR(); LGKM0(); MM(0, 1); BAR();
  RA(65536, 1);
  BAR(); LGKM0(); MM(1, 1); BAR();
  MM(1, 0);

  // ---- epilogue ----
  const int crow = g * 4;
#pragma unroll
  for (int i = 0; i < 8; i++) {
#pragma unroll
    for (int j = 0; j < 4; j++) {
      int col = n0 + wn * 64 + j * 16 + fr;
      float bcol = (MODE == 3) ? 0.f : bias[col];
      short sh[4];
#pragma unroll
      for (int r = 0; r < 4; r++) {
        int row = m0 + wm * 128 + i * 16 + crow + r;
        float v = acc[i][j][r] + bcol;
        if (MODE == 4) {
          sh[r] = f2bf(v);
          ((short*)outp)[(size_t)row * N + col] = sh[r];
        } else if (MODE == 2) {
          float y = 0.79788456f * (v + 0.044715f * v * v * v);
          float e = __builtin_amdgcn_exp2f(y * 2.885390082f);
          float th = 1.0f - 2.0f * __builtin_amdgcn_rcpf(e + 1.0f);
          v = 0.5f * v * (1.0f + th);
          ((short*)outp)[(size_t)row * N + col] = f2bf(v);
        } else {
          short* pp = (short*)outp + (size_t)zp * M * N;
          pp[(size_t)row * N + col] = f2bf(v);
        }
      }
      if (MODE == 4 && col >= 2048) {
        // transposed V write: Vt[(bh*64+d)*Ss + s], 4 consecutive s per lane
        int hd = col - 2048;
        int rbase = m0 + wm * 128 + i * 16 + crow;
        int bq = rbase >> 11, sb = rbase & 2047;
        int bh = bq * 16 + (hd >> 6), d = hd & 63;
        short4v pk;
        pk.x = sh[0]; pk.y = sh[1]; pk.z = sh[2]; pk.w = sh[3];
        *(short4v*)(vtp + (size_t)(bh * 64 + d) * Ss + sb) = pk;
      }
    }
  }
}

// ---------------- qkv GEMM (+fused V transpose): 192 blocks, 4m x 6n/XCD -----
__global__ __launch_bounds__(512, 2) void k_gemm_qkv(const short* __restrict__ A,
                                                     const short* __restrict__ Bt,
                                                     const float* __restrict__ bias,
                                                     short* __restrict__ o,
                                                     short* __restrict__ Vt) {
  extern __shared__ char smem[];
  int xcd = blockIdx.x & 7, u = blockIdx.x >> 3;
  int m0 = ((xcd >> 1) * 4 + u / 6) * 256;
  int n0 = ((xcd & 1) * 6 + u % 6) * 256;
  gemm256<4>(A, Bt, bias, o, Vt, 4096, 3072, 1024, m0, n0, 0, 0, 16, smem);
}

// ---------------- fc GEMM+GELU: 256 blocks, 4m x 8n per XCD ------------------
__global__ __launch_bounds__(512, 2) void k_gemm_fc(const short* __restrict__ A,
                                                    const short* __restrict__ Bt,
                                                    const float* __restrict__ bias,
                                                    short* __restrict__ o) {
  extern __shared__ char smem[];
  int xcd = blockIdx.x & 7, u = blockIdx.x >> 3;
  int m0 = ((xcd >> 1) * 4 + (u >> 3)) * 256;
  int n0 = ((xcd & 1) * 8 + (u & 7)) * 256;
  gemm256<2>(A, Bt, bias, o, nullptr, 4096, 4096, 1024, m0, n0, 0, 0, 16, smem);
}

// ---------------- wo projection: 256 blocks, split-K=4 -----------------------
__global__ __launch_bounds__(512, 2) void k_gemm_wo(const short* __restrict__ A,
                                                    const short* __restrict__ Bt,
                                                    short* __restrict__ parts) {
  extern __shared__ char smem[];
  int xcd = blockIdx.x & 7, u = blockIdx.x >> 3;
  int z = u >> 3;
  int m0 = (xcd * 2 + ((u >> 2) & 1)) * 256;
  int n0 = (u & 3) * 256;
  gemm256<3>(A, Bt, nullptr, parts, nullptr, 4096, 1024, 1024, m0, n0, z,
             z * 256, 4, smem);
}

// ---------------- pr projection: 256 blocks, split-K=4 -----------------------
__global__ __launch_bounds__(512, 2) void k_gemm_pr(const short* __restrict__ A,
                                                    const short* __restrict__ Bt,
                                                    short* __restrict__ parts) {
  extern __shared__ char smem[];
  int xcd = blockIdx.x & 7, u = blockIdx.x >> 3;
  int z = u >> 3;
  int m0 = (xcd * 2 + ((u >> 2) & 1)) * 256;
  int n0 = (u & 3) * 256;
  gemm256<3>(A, Bt, nullptr, parts, nullptr, 4096, 1024, 4096, m0, n0, z,
             z * 1024, 16, smem);
}

// ---------------- flash attention, early-issue prefetch staging --------------
__global__ __launch_bounds__(256) void flash_kernel(const short* __restrict__ qkv,
                                                    const short* __restrict__ Vt,
                                                    short* __restrict__ att) {
  __shared__ __align__(16) short Ks[4096];
  __shared__ __align__(16) short Vs[4096];
  __shared__ __align__(16) short P[4][16 * 72];
  const int w = threadIdx.x >> 6, lane = threadIdx.x & 63;
  const int qb = 31 - (blockIdx.x >> 5);
  const int bh = blockIdx.x & 31;
  const int b = bh >> 4, h = bh & 15;
  const int qbase = qb * 64 + w * 16;
  const int q = lane & 15;
  const int g = lane >> 4;
  const int fk = g * 8;
  short* Pw = &P[w][0];

  const int L0 = w * 64 + lane, L1 = L0 + 256;
  const int r0 = L0 >> 3, c0 = (L0 & 7) ^ (r0 & 7);
  const int r1 = L1 >> 3, c1 = (L1 & 7) ^ (r1 & 7);
  const short* kg0 = qkv + (size_t)(b * Ss + r0) * 3072 + 1024 + h * 64 + c0 * 8;
  const short* kg1 = qkv + (size_t)(b * Ss + r1) * 3072 + 1024 + h * 64 + c1 * 8;
  const short* vg0 = Vt + (size_t)(bh * 64 + r0) * Ss + c0 * 8;
  const short* vg1 = Vt + (size_t)(bh * 64 + r1) * Ss + c1 * 8;

  short8 qf[2];
  {
    const short* qrow = qkv + (size_t)(b * Ss + qbase + q) * 3072 + h * 64;
    qf[0] = *(const short8*)(qrow + fk);
    qf[1] = *(const short8*)(qrow + 32 + fk);
  }
  float4v o[4] = {};
  float l_i = 0.f;
  const float sc = 0.125f * 1.44269504088896f;
  const int nkt = qb + 1;

  // prologue staging for kt = 0
  gl_lds16(kg0, Ks + L0 * 8);
  gl_lds16(kg1, Ks + L1 * 8);
  gl_lds16(vg0, Vs + L0 * 8);
  gl_lds16(vg1, Vs + L1 * 8);

  for (int kt = 0; kt < nkt; kt++) {
    const int kbase = kt * 64;
    __syncthreads();  // staging for kt complete

    short8 kf[4][2], vf[4][2];
#pragma unroll
    for (int t = 0; t < 4; t++) {
      const int row = 16 * t + q;
      const int sw = (g ^ (row & 7)) * 8;
      kf[t][0] = *(const short8*)(Ks + row * 64 + sw);
      kf[t][1] = *(const short8*)(Ks + row * 64 + (sw ^ 32));
      vf[t][0] = *(const short8*)(Vs + row * 64 + sw);
      vf[t][1] = *(const short8*)(Vs + row * 64 + (sw ^ 32));
    }
    __syncthreads();  // all waves consumed Ks/Vs
    if (kt + 1 < nkt) {
      const size_t nb = (size_t)(kbase + 64);
      gl_lds16(kg0 + nb * 3072, Ks + L0 * 8);
      gl_lds16(kg1 + nb * 3072, Ks + L1 * 8);
      gl_lds16(vg0 + nb, Vs + L0 * 8);
      gl_lds16(vg1 + nb, Vs + L1 * 8);
    }

    float4v s[4] = {};
#pragma unroll
    for (int t = 0; t < 4; t++) {
      s[t] = MFMA(kf[t][0], qf[0], s[t]);
      s[t] = MFMA(kf[t][1], qf[1], s[t]);
    }
    const bool maskt = (kbase + 63 > qbase);
    const int qlim = qbase + q - kbase;
    float p[4][4];
    float rs = 0.f;
#pragma unroll
    for (int t = 0; t < 4; t++) {
#pragma unroll
      for (int r = 0; r < 4; r++) {
        float v = s[t][r] * sc;
        if (maskt && (16 * t + 4 * g + r > qlim)) v = -3.0e38f;
        float e = __builtin_amdgcn_exp2f(v);
        p[t][r] = e;
        rs += e;
      }
    }
    rs += __shfl_xor(rs, 16);
    rs += __shfl_xor(rs, 32);
    l_i += rs;
#pragma unroll
    for (int t = 0; t < 4; t++) {
      unsigned lo = (unsigned)(unsigned short)f2bf(p[t][0]) |
                    ((unsigned)(unsigned short)f2bf(p[t][1]) << 16);
      unsigned hi = (unsigned)(unsigned short)f2bf(p[t][2]) |
                    ((unsigned)(unsigned short)f2bf(p[t][3]) << 16);
      uint2 u; u.x = lo; u.y = hi;
      *(uint2*)(Pw + q * 72 + 16 * t + 4 * g) = u;
    }
    asm volatile("s_waitcnt lgkmcnt(0)" ::: "memory");
    short8 pb0 = *(const short8*)(Pw + q * 72 + fk);
    short8 pb1 = *(const short8*)(Pw + q * 72 + 32 + fk);
#pragma unroll
    for (int t = 0; t < 4; t++) {
      o[t] = MFMA(vf[t][0], pb0, o[t]);
      o[t] = MFMA(vf[t][1], pb1, o[t]);
    }
  }
  const float inv = 1.0f / l_i;
  const int orow = b * Ss + qbase + q;
#pragma unroll
  for (int t = 0; t < 4; t++) {
    short4v ov;
    ov.x = f2bf(o[t][0] * inv);
    ov.y = f2bf(o[t][1] * inv);
    ov.z = f2bf(o[t][2] * inv);
    ov.w = f2bf(o[t][3] * inv);
    *(short4v*)(att + (size_t)orow * Dd + h * 64 + 16 * t + 4 * g) = ov;
  }
}

extern "C" void kernel_launch(void* const* d_in, const int* in_sizes, int n_in,
                              void* d_out, int out_size, void* d_ws, size_t ws_size,
                              hipStream_t stream) {
  const float* x    = (const float*)d_in[0];
  const float* Wqkv = (const float*)d_in[1];
  const float* bqkv = (const float*)d_in[2];
  const float* Wo   = (const float*)d_in[3];
  const float* bo   = (const float*)d_in[4];
  const float* Wfc  = (const float*)d_in[5];
  const float* bfc  = (const float*)d_in[6];
  const float* Wpr  = (const float*)d_in[7];
  const float* bpr  = (const float*)d_in[8];
  const float* g1   = (const float*)d_in[9];
  const float* be1  = (const float*)d_in[10];
  const float* g2   = (const float*)d_in[11];
  const float* be2  = (const float*)d_in[12];

  char* ws = (char*)d_ws;
  const size_t MB = 1024 * 1024;
  short* h1     = (short*)(ws + 0);        // [0,8)
  short* qkvb   = (short*)(ws + 8 * MB);   // [8,32)
  short* partWo = (short*)(ws + 0);        // [0,32), after flash (h1/qkvb dead)
  short* partPr = (short*)(ws + 0);        // [0,32), after fc (partWo dead)
  short* Vt     = (short*)(ws + 32 * MB);  // [32,40)
  short* att    = (short*)(ws + 40 * MB);  // [40,48)
  float* x1     = (float*)(ws + 48 * MB);  // [48,64)
  short* h2     = (short*)(ws + 64 * MB);  // [64,72)
  short* geluo  = (short*)(ws + 72 * MB);  // [72,104)
  short* WtQkv  = (short*)(ws + 104 * MB);
  short* WtO    = (short*)(ws + 110 * MB);
  short* WtFc   = (short*)(ws + 112 * MB);
  short* WtPr   = (short*)(ws + 120 * MB);

  prep_kernel<<<16384, 256, 0, stream>>>(Wqkv, WtQkv, Wo, WtO, Wfc, WtFc,
                                         Wpr, WtPr, x, g1, be1, h1);
  k_gemm_qkv<<<192, 512, 131072, stream>>>(h1, WtQkv, bqkv, qkvb, Vt);
  flash_kernel<<<1024, 256, 0, stream>>>(qkvb, Vt, att);
  k_gemm_wo<<<256, 512, 131072, stream>>>(att, WtO, partWo);
  reduce_ln_kernel<<<4096, 256, 0, stream>>>(x, bo, partWo, g2, be2, x1, h2);
  k_gemm_fc<<<256, 512, 131072, stream>>>(h2, WtFc, bfc, geluo);
  k_gemm_pr<<<256, 512, 131072, stream>>>(geluo, WtPr, partPr);
  reduce_kernel<<<4096, 256, 0, stream>>>(x1, bpr, partPr, (float*)d_out);
}